// Round 7
// baseline (8561.002 us; speedup 1.0000x reference)
//
#include <hip/hip_runtime.h>
#include <hip/hip_bf16.h>
#include <cstdint>
#include <cstring>

typedef short short8  __attribute__((ext_vector_type(8)));
typedef float floatx4 __attribute__((ext_vector_type(4)));

#define HID    128
#define NB     32
#define TPB    256
#define NBLK   2048          // 65536 / 32
#define TSTEPS 30
#define MU_OFF 5898240       // 65536*30*3

// ws layout (bf16 units): A-fragment-swizzled weight arrays, hi then lo per set
#define L0_SZ  81920         // 512*160  (K-ext: [Whh(128)|Wih0(3)|bias(1)|0(28)])
#define L1_SZ  131072        // 512*256  (K-ext: [Wih1(128)|Whh1(128)])
#define ENC0_HI 0
#define ENC0_LO 81920
#define ENC1_HI 163840
#define ENC1_LO 294912
#define DEC0_HI 425984
#define DEC0_LO 507904
#define DEC1_HI 589824
#define DEC1_LO 720896

#define S0 144               // h0 row stride: blocks 0..15 h (XOR-swizzled), +128 x/bias
#define S1 128               // h1 row stride: 16 blocks

__device__ __forceinline__ float sigm(float v){ return 1.f/(1.f+__expf(-v)); }
__device__ __forceinline__ float tanh_fast(float v){ return 2.f/(1.f+__expf(-2.f*v)) - 1.f; }

__device__ __forceinline__ unsigned short f2bf(float f){
  unsigned u = __float_as_uint(f);
  u = (u + 0x7FFF + ((u>>16)&1)) >> 16;     // RNE; inputs finite
  return (unsigned short)u;
}
__device__ __forceinline__ float bf2f(unsigned short b){
  return __uint_as_float(((unsigned)b)<<16);
}
// packed RNE f32x2 -> bf16x2 (v_cvt_pk_bf16_f32); a -> low16, b -> high16
__device__ __forceinline__ unsigned cvt_pk(float a, float b){
  float2 f2; f2.x = a; f2.y = b;
  __hip_bfloat162 h = __float22bfloat162_rn(f2);
  unsigned u; __builtin_memcpy(&u, &h, 4);
  return u;
}

// ---------------- prep: swizzle weights into A-fragment order, bf16 hi/lo ----
// A-frag element (mt, kt, lane l, jj):  A[mt*16 + (l&15)][kt*32 + ((l>>4)&3)*8 + jj]
// stored at ((mt*KT + kt)*64 + l)*8 + jj   -> consumer does 1 coalesced b128/lane
// Layer0 K-ext columns: k<128 Whh | 128..130 Wih0 | 131 bias (B==1.0) | rest 0
extern "C" __global__ void __launch_bounds__(256)
prep_frag(const float* __restrict__ eWih0, const float* __restrict__ eWhh0,
          const float* __restrict__ eB0,
          const float* __restrict__ eWih1, const float* __restrict__ eWhh1,
          const float* __restrict__ dWih0, const float* __restrict__ dWhh0,
          const float* __restrict__ dB0,
          const float* __restrict__ dWih1, const float* __restrict__ dWhh1,
          unsigned short* __restrict__ ws)
{
  const int idx = blockIdx.x*256 + threadIdx.x;   // one thread -> one (hi,lo) pair
  int i2, hi_base, lo_base, KT;
  const float* Wa; const float* Wb; const float* Bv;
  if (idx < L0_SZ)                { i2=idx;                 hi_base=ENC0_HI; lo_base=ENC0_LO; Wa=eWhh0; Wb=eWih0; Bv=eB0; KT=5; }
  else if (idx < L0_SZ+L1_SZ)     { i2=idx-L0_SZ;           hi_base=ENC1_HI; lo_base=ENC1_LO; Wa=eWih1; Wb=eWhh1; Bv=0;   KT=8; }
  else if (idx < 2*L0_SZ+L1_SZ)   { i2=idx-(L0_SZ+L1_SZ);   hi_base=DEC0_HI; lo_base=DEC0_LO; Wa=dWhh0; Wb=dWih0; Bv=dB0; KT=5; }
  else                            { i2=idx-(2*L0_SZ+L1_SZ); hi_base=DEC1_HI; lo_base=DEC1_LO; Wa=dWih1; Wb=dWhh1; Bv=0;   KT=8; }
  const int jj = i2 & 7, l = (i2>>3)&63, tk = i2>>9;
  const int kt = (KT==5) ? (tk%5) : (tk&7);
  const int mt = (KT==5) ? (tk/5) : (tk>>3);
  const int row = mt*16 + (l&15);
  const int k   = kt*32 + ((l>>4)&3)*8 + jj;
  float w;
  if (KT==5){
    if      (k < 128) w = Wa[row*128+k];
    else if (k < 131) w = Wb[row*3 + (k-128)];
    else if (k ==131) w = Bv[row];
    else              w = 0.f;
  } else {
    w = (k<128) ? Wa[row*128+k] : Wb[row*128 + (k-128)];
  }
  const unsigned short hi = f2bf(w);
  ws[hi_base + i2] = hi;
  ws[lo_base + i2] = f2bf(w - bf2f(hi));
}

// ---------------- fused LSTM: NB=32/block, 4 waves, 3 blocks/CU (no spill) --
extern "C" __global__ void __launch_bounds__(TPB, 3)
lstm_mfma(const float* __restrict__ x,
          const unsigned short* __restrict__ wf,
          const float* __restrict__ enc_b1, const float* __restrict__ dec_b1,
          const float* __restrict__ fc_W,  const float* __restrict__ fc_b,
          float* __restrict__ out)
{
  // h in B-frag layout: element (n,k) k<128 at n*S + ((k>>3)^(n&7))*8 + (k&7)
  // x/bias region (layer0 only): n*S0 + 128 + c  (c=0..2 x, c=3 const 1.0)
  __shared__ unsigned short h0h[NB*S0], h0l[NB*S0];   // 9216 B each
  __shared__ unsigned short h1h[NB*S1], h1l[NB*S1];   // 8192 B each
  __shared__ float bias1[512];                        // layer1 bias (enc, later dec)
  __shared__ float fcw[6*HID];
  __shared__ float fcb[8];

  const int tid  = threadIdx.x;
  const int w    = tid>>6, l = tid&63;
  const int quad = (l>>4)&3, n15 = l&15, q7 = n15&7;
  const int b0   = blockIdx.x*NB;

  for (int i=tid;i<512;i+=TPB) bias1[i]=enc_b1[i];
  for (int i=tid;i<6*HID;i+=TPB) fcw[i]=fc_W[i];
  if (tid<6) fcb[tid]=fc_b[tid];
  for (int i=tid;i<NB*S0;i+=TPB){ h0h[i]=0; h0l[i]=0; }
  for (int i=tid;i<NB*S1;i+=TPB){ h1h[i]=0; h1l[i]=0; }
  __syncthreads();
  if (tid < NB) h0h[tid*S0 + 131] = 0x3F80;   // B==1.0 for the bias column
  __syncthreads();

  auto write_x = [&](int t){
    if (tid < 96){
      const int n = tid & 31, c = tid >> 5;
      const float v = x[(size_t)(b0+n)*90 + t*3 + c];
      const int idx = n*S0 + 128 + c;
      const unsigned short hi = f2bf(v);
      h0h[idx] = hi; h0l[idx] = f2bf(v - bf2f(hi));
    }
  };
  write_x(0);
  __syncthreads();

  // wave w owns m-tiles mt = g*8 + w*2 + s  (g=gate, s=0,1), i.e. j in [32w,32w+32)
  floatx4 acc[8][2];                 // [g*2+s][nt]
  float c0[2][2][4], c1[2][2][4];    // [s][nt][r]
#pragma unroll
  for (int s=0;s<2;s++)
#pragma unroll
    for (int nt=0;nt<2;nt++)
#pragma unroll
      for (int r=0;r<4;r++){ c0[s][nt][r]=0.f; c1[s][nt][r]=0.f; }

  auto zacc = [&]{
    const floatx4 z = {0.f,0.f,0.f,0.f};
#pragma unroll
    for (int p=0;p<8;p++){ acc[p][0]=z; acc[p][1]=z; }
  };

  auto mfma_block = [&](const unsigned short* __restrict__ Ahi,
                        const unsigned short* __restrict__ Alo, int KT, int kt,
                        const short8 (&bh)[2], const short8 (&bl)[2]){
#pragma unroll
    for (int p=0;p<8;p++){
      const int mt = (p>>1)*8 + w*2 + (p&1);
      const int ao = ((mt*KT + kt)*64 + l)*8;
      const short8 ah = *(const short8*)(Ahi + ao);
      const short8 al = *(const short8*)(Alo + ao);
      acc[p][0] = __builtin_amdgcn_mfma_f32_16x16x32_bf16(ah, bh[0], acc[p][0],0,0,0);
      acc[p][1] = __builtin_amdgcn_mfma_f32_16x16x32_bf16(ah, bh[1], acc[p][1],0,0,0);
      acc[p][0] = __builtin_amdgcn_mfma_f32_16x16x32_bf16(ah, bl[0], acc[p][0],0,0,0);
      acc[p][1] = __builtin_amdgcn_mfma_f32_16x16x32_bf16(ah, bl[1], acc[p][1],0,0,0);
      acc[p][0] = __builtin_amdgcn_mfma_f32_16x16x32_bf16(al, bh[0], acc[p][0],0,0,0);
      acc[p][1] = __builtin_amdgcn_mfma_f32_16x16x32_bf16(al, bh[1], acc[p][1],0,0,0);
    }
  };

  // layer0: kt 0..3 swizzled h-blocks; kt=4 fixed x/bias block (quads share,
  // don't-care columns multiply zero A-weights)
  auto mv0 = [&](const unsigned short* __restrict__ Ahi,
                 const unsigned short* __restrict__ Alo){
#pragma unroll 1
    for (int kt=0; kt<4; ++kt){
      const int bo = (((kt*4+quad)^q7)<<3);
      short8 bh[2], bl[2];
#pragma unroll
      for (int nt=0;nt<2;nt++){
        const int ro = (nt*16+n15)*S0 + bo;
        bh[nt] = *(const short8*)(h0h + ro);
        bl[nt] = *(const short8*)(h0l + ro);
      }
      mfma_block(Ahi, Alo, 5, kt, bh, bl);
    }
    {
      short8 bh[2], bl[2];
#pragma unroll
      for (int nt=0;nt<2;nt++){
        const int ro = (nt*16+n15)*S0 + 128;
        bh[nt] = *(const short8*)(h0h + ro);
        bl[nt] = *(const short8*)(h0l + ro);
      }
      mfma_block(Ahi, Alo, 5, 4, bh, bl);
    }
  };

  // layer1: kt 0..3 from h0, kt 4..7 from h1
  auto mv1 = [&](const unsigned short* __restrict__ Ahi,
                 const unsigned short* __restrict__ Alo){
#pragma unroll 1
    for (int kt=0; kt<8; ++kt){
      const unsigned short* Bh = (kt<4) ? h0h : h1h;
      const unsigned short* Bl = (kt<4) ? h0l : h1l;
      const int SS  = (kt<4) ? S0 : S1;
      const int bo  = ((((kt&3)*4+quad)^q7)<<3);
      short8 bh[2], bl[2];
#pragma unroll
      for (int nt=0;nt<2;nt++){
        const int ro = (nt*16+n15)*SS + bo;
        bh[nt] = *(const short8*)(Bh + ro);
        bl[nt] = *(const short8*)(Bl + ro);
      }
      mfma_block(Ahi, Alo, 8, kt, bh, bl);
    }
  };

  // activations in-register; inner barrier, then packed b64 h-writes.
  // bs == nullptr: bias already folded into MFMA (layer0).
  auto cell_update = [&](float (&cst)[2][2][4], const float* bs,
                         unsigned short* Hh, unsigned short* Hl, int SS){
    float hv[2][2][4];
#pragma unroll
    for (int s=0;s<2;s++)
#pragma unroll
      for (int nt=0;nt<2;nt++)
#pragma unroll
        for (int r=0;r<4;r++){
          const int j = (w*2+s)*16 + quad*4 + r;
          float gi = acc[0+s][nt][r], gf = acc[2+s][nt][r];
          float gg = acc[4+s][nt][r], go = acc[6+s][nt][r];
          if (bs){ gi += bs[j]; gf += bs[128+j]; gg += bs[256+j]; go += bs[384+j]; }
          const float i_ = sigm(gi);
          const float f_ = sigm(gf);
          const float g_ = tanh_fast(gg);
          const float o_ = sigm(go);
          const float c  = f_*cst[s][nt][r] + i_*g_;
          cst[s][nt][r] = c;
          hv[s][nt][r]  = o_*tanh_fast(c);
        }
    __syncthreads();                 // all waves done READING old h
#pragma unroll
    for (int s=0;s<2;s++)
#pragma unroll
      for (int nt=0;nt<2;nt++){
        const int jb = (w*2+s)*2 + (quad>>1);        // j>>3
        const int n  = nt*16 + n15;
        const int base = n*SS + ((jb ^ (n&7))<<3) + ((quad&1)<<2);
        uint2 ph, pl;
#pragma unroll
        for (int rp=0;rp<2;rp++){
          const float a = hv[s][nt][rp*2], b = hv[s][nt][rp*2+1];
          const unsigned hb = cvt_pk(a, b);
          const float ra = a - __uint_as_float(hb<<16);
          const float rb = b - __uint_as_float(hb & 0xFFFF0000u);
          ((unsigned*)&ph)[rp] = hb;
          ((unsigned*)&pl)[rp] = cvt_pk(ra, rb);
        }
        *(uint2*)(Hh + base) = ph;                // ds_write_b64
        *(uint2*)(Hl + base) = pl;
      }
  };

  // -------------------- encoder (3 barriers/timestep) --------------------
#pragma unroll 1
  for (int t=0; t<TSTEPS; ++t){
    zacc();
    mv0(wf+ENC0_HI, wf+ENC0_LO);
    cell_update(c0, nullptr, h0h, h0l, S0);
    if (t+1 < TSTEPS) write_x(t+1);      // x-region disjoint from h writes
    __syncthreads();
    zacc();
    mv1(wf+ENC1_HI, wf+ENC1_LO);
    cell_update(c1, bias1, h1h, h1l, S1);
    // no trailing barrier: next mv0 touches only h0/x; h1 visibility is
    // guaranteed by the two barriers inside the next timestep before mv1.
  }
  // h0 x-region still holds x[:,29,:] == decoder's initial input

  // refill bias1 with decoder layer-1 bias: all enc bias1 reads complete
  // (they precede cell_update's internal barrier, which every wave passed)
  for (int i=tid;i<512;i+=TPB) bias1[i]=dec_b1[i];
  __syncthreads();

  // -------------------- decoder --------------------
#pragma unroll 1
  for (int t=0; t<TSTEPS; ++t){
    zacc();
    mv0(wf+DEC0_HI, wf+DEC0_LO);
    cell_update(c0, nullptr, h0h, h0l, S0);
    __syncthreads();
    zacc();
    mv1(wf+DEC1_HI, wf+DEC1_LO);
    cell_update(c1, bias1, h1h, h1l, S1);
    __syncthreads();                     // h1_t visible for FC

    // FC head: stats[6][32] = fcW @ h1 + fcb; mu fed back into h0 x-region
    if (tid < 192){
      const int n = tid & 31, oi = tid >> 5;
      float s = fcb[oi];
#pragma unroll 4
      for (int blk=0; blk<16; ++blk){
        const int ro = n*S1 + ((blk^(n&7))<<3);
        const short8 hh = *(const short8*)(h1h + ro);
        const short8 hl = *(const short8*)(h1l + ro);
#pragma unroll
        for (int jj=0;jj<8;++jj)
          s += fcw[oi*HID + blk*8 + jj] *
               (bf2f((unsigned short)hh[jj]) + bf2f((unsigned short)hl[jj]));
      }
      const size_t off = (size_t)(b0+n)*90 + (size_t)t*3;
      if (oi < 3){
        out[off + oi] = s;
        const int idx = n*S0 + 128 + oi;
        const unsigned short hi = f2bf(s);
        h0h[idx] = hi; h0l[idx] = f2bf(s - bf2f(hi));
      } else {
        out[MU_OFF + off + (oi-3)] = s;
      }
    }
    __syncthreads();
  }
}

extern "C" void kernel_launch(void* const* d_in, const int* in_sizes, int n_in,
                              void* d_out, int out_size, void* d_ws, size_t ws_size,
                              hipStream_t stream) {
  const float* x        = (const float*)d_in[0];
  const float* enc_Wih0 = (const float*)d_in[1];
  const float* enc_Whh0 = (const float*)d_in[2];
  const float* enc_b0   = (const float*)d_in[3];
  const float* enc_Wih1 = (const float*)d_in[4];
  const float* enc_Whh1 = (const float*)d_in[5];
  const float* enc_b1   = (const float*)d_in[6];
  const float* dec_Wih0 = (const float*)d_in[7];
  const float* dec_Whh0 = (const float*)d_in[8];
  const float* dec_b0   = (const float*)d_in[9];
  const float* dec_Wih1 = (const float*)d_in[10];
  const float* dec_Whh1 = (const float*)d_in[11];
  const float* dec_b1   = (const float*)d_in[12];
  const float* fc_W     = (const float*)d_in[13];
  const float* fc_b     = (const float*)d_in[14];
  unsigned short* ws = (unsigned short*)d_ws;
  float* out = (float*)d_out;

  // 425,984 (hi,lo) pairs -> exactly 1664 blocks of 256
  prep_frag<<<1664, 256, 0, stream>>>(
      enc_Wih0, enc_Whh0, enc_b0, enc_Wih1, enc_Whh1,
      dec_Wih0, dec_Whh0, dec_b0, dec_Wih1, dec_Whh1, ws);

  lstm_mfma<<<NBLK, TPB, 0, stream>>>(
      x, ws, enc_b1, dec_b1, fc_W, fc_b, out);
}

// Round 8
// 8490.676 us; speedup vs baseline: 1.0083x; 1.0083x over previous
//
#include <hip/hip_runtime.h>
#include <cstdint>

typedef short short8  __attribute__((ext_vector_type(8)));
typedef unsigned short ushort4v __attribute__((ext_vector_type(4)));
typedef float floatx4 __attribute__((ext_vector_type(4)));

#define HID    128
#define NB     32
#define TPB    256
#define NBLK   2048          // 65536 / 32
#define TSTEPS 30
#define MU_OFF 5898240       // 65536*30*3

// ws layout (bf16 units): A-fragment-swizzled weight arrays, hi then lo per set
#define L0_SZ  81920         // 512*160  (K-ext: [Whh(128)|Wih0(3)|bias(1)|0(28)])
#define L1_SZ  131072        // 512*256  (K-ext: [Wih1(128)|Whh1(128)])
#define ENC0_HI 0
#define ENC0_LO 81920
#define ENC1_HI 163840
#define ENC1_LO 294912
#define DEC0_HI 425984
#define DEC0_LO 507904
#define DEC1_HI 589824
#define DEC1_LO 720896

#define S0 192               // h0 row stride (r4-proven): base ≡ 0 mod 32 dwords,
                             // XOR swizzle alone spreads banks -> b128 floor
#define S1 128               // h1 row stride

__device__ __forceinline__ float sigm(float v){ return 1.f/(1.f+__expf(-v)); }
__device__ __forceinline__ float tanh_fast(float v){ return 2.f/(1.f+__expf(-2.f*v)) - 1.f; }

__device__ __forceinline__ unsigned short f2bf(float f){
  unsigned u = __float_as_uint(f);
  u = (u + 0x7FFF + ((u>>16)&1)) >> 16;     // RNE; inputs finite
  return (unsigned short)u;
}
__device__ __forceinline__ float bf2f(unsigned short b){
  return __uint_as_float(((unsigned)b)<<16);
}

// ---------------- prep: swizzle weights into A-fragment order, bf16 hi/lo ----
// A-frag element (mt, kt, lane l, jj):  A[mt*16 + (l&15)][kt*32 + ((l>>4)&3)*8 + jj]
// stored at ((mt*KT + kt)*64 + l)*8 + jj   -> consumer does 1 coalesced b128/lane
// Layer0 K-ext columns: k<128 Whh | 128..130 Wih0 | 131 bias (B==1.0) | rest 0
extern "C" __global__ void __launch_bounds__(256)
prep_frag(const float* __restrict__ eWih0, const float* __restrict__ eWhh0,
          const float* __restrict__ eB0,
          const float* __restrict__ eWih1, const float* __restrict__ eWhh1,
          const float* __restrict__ dWih0, const float* __restrict__ dWhh0,
          const float* __restrict__ dB0,
          const float* __restrict__ dWih1, const float* __restrict__ dWhh1,
          unsigned short* __restrict__ ws)
{
  const int idx = blockIdx.x*256 + threadIdx.x;   // one thread -> one (hi,lo) pair
  int i2, hi_base, lo_base, KT;
  const float* Wa; const float* Wb; const float* Bv;
  if (idx < L0_SZ)                { i2=idx;                 hi_base=ENC0_HI; lo_base=ENC0_LO; Wa=eWhh0; Wb=eWih0; Bv=eB0; KT=5; }
  else if (idx < L0_SZ+L1_SZ)     { i2=idx-L0_SZ;           hi_base=ENC1_HI; lo_base=ENC1_LO; Wa=eWih1; Wb=eWhh1; Bv=0;   KT=8; }
  else if (idx < 2*L0_SZ+L1_SZ)   { i2=idx-(L0_SZ+L1_SZ);   hi_base=DEC0_HI; lo_base=DEC0_LO; Wa=dWhh0; Wb=dWih0; Bv=dB0; KT=5; }
  else                            { i2=idx-(2*L0_SZ+L1_SZ); hi_base=DEC1_HI; lo_base=DEC1_LO; Wa=dWih1; Wb=dWhh1; Bv=0;   KT=8; }
  const int jj = i2 & 7, l = (i2>>3)&63, tk = i2>>9;
  const int kt = (KT==5) ? (tk%5) : (tk&7);
  const int mt = (KT==5) ? (tk/5) : (tk>>3);
  const int row = mt*16 + (l&15);
  const int k   = kt*32 + ((l>>4)&3)*8 + jj;
  float w;
  if (KT==5){
    if      (k < 128) w = Wa[row*128+k];
    else if (k < 131) w = Wb[row*3 + (k-128)];
    else if (k ==131) w = Bv[row];
    else              w = 0.f;
  } else {
    w = (k<128) ? Wa[row*128+k] : Wb[row*128 + (k-128)];
  }
  const unsigned short hi = f2bf(w);
  ws[hi_base + i2] = hi;
  ws[lo_base + i2] = f2bf(w - bf2f(hi));
}

// ---------------- fused LSTM: NB=32/block, 4 waves, 3 blocks/CU -------------
extern "C" __global__ void __launch_bounds__(TPB, 3)
lstm_mfma(const float* __restrict__ x,
          const unsigned short* __restrict__ wf,
          const float* __restrict__ enc_b1, const float* __restrict__ dec_b1,
          const float* __restrict__ fc_W,  const float* __restrict__ fc_b,
          float* __restrict__ out)
{
  // h in B-frag layout: element (n,k) at n*S + ((k>>3)^(n&7))*8 + (k&7)
  // (holds for k<128 h, and for the x/bias columns 128..131 in block 16^swz)
  __shared__ unsigned short h0h[NB*S0], h0l[NB*S0];   // 12288 B each
  __shared__ unsigned short h1h[NB*S1], h1l[NB*S1];   // 8192 B each
  __shared__ float bias1[512];                        // layer1 bias (enc, later dec)
  __shared__ float fcw[6*HID];
  __shared__ float fcb[8];

  const int tid  = threadIdx.x;
  const int w    = tid>>6, l = tid&63;
  const int quad = (l>>4)&3, n15 = l&15, q7 = n15&7;
  const int b0   = blockIdx.x*NB;

  for (int i=tid;i<512;i+=TPB) bias1[i]=enc_b1[i];
  for (int i=tid;i<6*HID;i+=TPB) fcw[i]=fc_W[i];
  if (tid<6) fcb[tid]=fc_b[tid];
  for (int i=tid;i<NB*S0;i+=TPB){ h0h[i]=0; h0l[i]=0; }
  for (int i=tid;i<NB*S1;i+=TPB){ h1h[i]=0; h1l[i]=0; }
  __syncthreads();
  // bias column (k=131) B==1.0, in the swizzled block 16 of each row
  if (tid < NB) h0h[tid*S0 + ((16^(tid&7))<<3) + 3] = 0x3F80;
  __syncthreads();

  auto write_x = [&](int t){
    if (tid < 96){
      const int n = tid & 31, c = tid >> 5;
      const float v = x[(size_t)(b0+n)*90 + t*3 + c];
      const int idx = n*S0 + ((16^(n&7))<<3) + c;     // k = 128+c -> block 16
      const unsigned short hi = f2bf(v);
      h0h[idx] = hi; h0l[idx] = f2bf(v - bf2f(hi));
    }
  };
  write_x(0);
  __syncthreads();

  // wave w owns m-tiles mt = g*8 + w*2 + s  (g=gate, s=0,1), i.e. j in [32w,32w+32)
  floatx4 acc[8][2];                 // [g*2+s][nt]
  float c0[2][2][4], c1[2][2][4];    // [s][nt][r]
#pragma unroll
  for (int s=0;s<2;s++)
#pragma unroll
    for (int nt=0;nt<2;nt++)
#pragma unroll
      for (int r=0;r<4;r++){ c0[s][nt][r]=0.f; c1[s][nt][r]=0.f; }

  const floatx4 zf = {0.f,0.f,0.f,0.f};

  // kt==first: first MFMA per acc uses C=0 (kills the v_accvgpr zero-init)
  auto mfma_block = [&](const unsigned short* __restrict__ Ahi,
                        const unsigned short* __restrict__ Alo, int KT, int kt,
                        const short8 (&bh)[2], const short8 (&bl)[2], bool first){
#pragma unroll
    for (int p=0;p<8;p++){
      const int mt = (p>>1)*8 + w*2 + (p&1);
      const int ao = ((mt*KT + kt)*64 + l)*8;
      const short8 ah = *(const short8*)(Ahi + ao);
      const short8 al = *(const short8*)(Alo + ao);
      acc[p][0] = __builtin_amdgcn_mfma_f32_16x16x32_bf16(ah, bh[0], first ? zf : acc[p][0],0,0,0);
      acc[p][1] = __builtin_amdgcn_mfma_f32_16x16x32_bf16(ah, bh[1], first ? zf : acc[p][1],0,0,0);
      acc[p][0] = __builtin_amdgcn_mfma_f32_16x16x32_bf16(ah, bl[0], acc[p][0],0,0,0);
      acc[p][1] = __builtin_amdgcn_mfma_f32_16x16x32_bf16(ah, bl[1], acc[p][1],0,0,0);
      acc[p][0] = __builtin_amdgcn_mfma_f32_16x16x32_bf16(al, bh[0], acc[p][0],0,0,0);
      acc[p][1] = __builtin_amdgcn_mfma_f32_16x16x32_bf16(al, bh[1], acc[p][1],0,0,0);
    }
  };

  // layer0: K=160, 5 kt, all from h0 (kt=4 covers x cols 128-130, bias 131,
  // zeros beyond; quads 1-3 of kt=4 read don't-care blocks x zero A-weights)
  auto mv0 = [&](const unsigned short* __restrict__ Ahi,
                 const unsigned short* __restrict__ Alo){
#pragma unroll 1
    for (int kt=0; kt<5; ++kt){
      const int bo = (((kt*4+quad)^q7)<<3);
      short8 bh[2], bl[2];
#pragma unroll
      for (int nt=0;nt<2;nt++){
        const int ro = (nt*16+n15)*S0 + bo;
        bh[nt] = *(const short8*)(h0h + ro);
        bl[nt] = *(const short8*)(h0l + ro);
      }
      mfma_block(Ahi, Alo, 5, kt, bh, bl, kt==0);
    }
  };

  // layer1: kt 0..3 from h0, kt 4..7 from h1
  auto mv1 = [&](const unsigned short* __restrict__ Ahi,
                 const unsigned short* __restrict__ Alo){
#pragma unroll 1
    for (int kt=0; kt<8; ++kt){
      const unsigned short* Bh = (kt<4) ? h0h : h1h;
      const unsigned short* Bl = (kt<4) ? h0l : h1l;
      const int SS  = (kt<4) ? S0 : S1;
      const int bo  = ((((kt&3)*4+quad)^q7)<<3);
      short8 bh[2], bl[2];
#pragma unroll
      for (int nt=0;nt<2;nt++){
        const int ro = (nt*16+n15)*SS + bo;
        bh[nt] = *(const short8*)(Bh + ro);
        bl[nt] = *(const short8*)(Bl + ro);
      }
      mfma_block(Ahi, Alo, 8, kt, bh, bl, kt==0);
    }
  };

  // activations in-register; inner barrier, then packed b64 h-writes.
  // bs == nullptr: bias already folded into MFMA (layer0).
  auto cell_update = [&](float (&cst)[2][2][4], const float* bs,
                         unsigned short* Hh, unsigned short* Hl, int SS){
    float hv[2][2][4];
#pragma unroll
    for (int s=0;s<2;s++)
#pragma unroll
      for (int nt=0;nt<2;nt++)
#pragma unroll
        for (int r=0;r<4;r++){
          const int j = (w*2+s)*16 + quad*4 + r;
          float gi = acc[0+s][nt][r], gf = acc[2+s][nt][r];
          float gg = acc[4+s][nt][r], go = acc[6+s][nt][r];
          if (bs){ gi += bs[j]; gf += bs[128+j]; gg += bs[256+j]; go += bs[384+j]; }
          const float i_ = sigm(gi);
          const float f_ = sigm(gf);
          const float g_ = tanh_fast(gg);
          const float o_ = sigm(go);
          const float c  = f_*cst[s][nt][r] + i_*g_;
          cst[s][nt][r] = c;
          hv[s][nt][r]  = o_*tanh_fast(c);
        }
    __syncthreads();                 // all waves done READING old h
#pragma unroll
    for (int s=0;s<2;s++)
#pragma unroll
      for (int nt=0;nt<2;nt++){
        const int jb = (w*2+s)*2 + (quad>>1);        // j>>3
        const int n  = nt*16 + n15;
        const int base = n*SS + ((jb ^ (n&7))<<3) + ((quad&1)<<2);
        ushort4v ph, pl;
#pragma unroll
        for (int r=0;r<4;r++){
          const unsigned short hi = f2bf(hv[s][nt][r]);
          ph[r] = hi;
          pl[r] = f2bf(hv[s][nt][r] - bf2f(hi));
        }
        *(ushort4v*)(Hh + base) = ph;                // ds_write_b64
        *(ushort4v*)(Hl + base) = pl;
      }
  };

  // -------------------- encoder (3 barriers/timestep) --------------------
#pragma unroll 1
  for (int t=0; t<TSTEPS; ++t){
    mv0(wf+ENC0_HI, wf+ENC0_LO);
    cell_update(c0, nullptr, h0h, h0l, S0);
    if (t+1 < TSTEPS) write_x(t+1);      // x-block disjoint from h-block writes
    __syncthreads();
    mv1(wf+ENC1_HI, wf+ENC1_LO);
    cell_update(c1, bias1, h1h, h1l, S1);
    // no trailing barrier: next mv0 touches only h0/x; h1 visibility is
    // guaranteed by the two barriers inside the next timestep before mv1.
  }
  // h0 x-block still holds x[:,29,:] == decoder's initial input

  // refill bias1 with decoder layer-1 bias: all enc bias1 reads precede the
  // internal barrier of the last cell_update, which every wave has passed.
  for (int i=tid;i<512;i+=TPB) bias1[i]=dec_b1[i];
  __syncthreads();

  // -------------------- decoder --------------------
#pragma unroll 1
  for (int t=0; t<TSTEPS; ++t){
    mv0(wf+DEC0_HI, wf+DEC0_LO);
    cell_update(c0, nullptr, h0h, h0l, S0);
    __syncthreads();
    mv1(wf+DEC1_HI, wf+DEC1_LO);
    cell_update(c1, bias1, h1h, h1l, S1);
    __syncthreads();                     // h1_t visible for FC

    // FC head: stats[6][32] = fcW @ h1 + fcb; mu fed back into h0 x-block
    if (tid < 192){
      const int n = tid & 31, oi = tid >> 5;
      float s = fcb[oi];
#pragma unroll 4
      for (int blk=0; blk<16; ++blk){
        const int ro = n*S1 + ((blk^(n&7))<<3);
        const short8 hh = *(const short8*)(h1h + ro);
        const short8 hl = *(const short8*)(h1l + ro);
#pragma unroll
        for (int jj=0;jj<8;++jj)
          s += fcw[oi*HID + blk*8 + jj] *
               (bf2f((unsigned short)hh[jj]) + bf2f((unsigned short)hl[jj]));
      }
      const size_t off = (size_t)(b0+n)*90 + (size_t)t*3;
      if (oi < 3){
        out[off + oi] = s;
        const int idx = n*S0 + ((16^(n&7))<<3) + oi;  // k = 128+oi
        const unsigned short hi = f2bf(s);
        h0h[idx] = hi; h0l[idx] = f2bf(s - bf2f(hi));
      } else {
        out[MU_OFF + off + (oi-3)] = s;
      }
    }
    __syncthreads();
  }
}

extern "C" void kernel_launch(void* const* d_in, const int* in_sizes, int n_in,
                              void* d_out, int out_size, void* d_ws, size_t ws_size,
                              hipStream_t stream) {
  const float* x        = (const float*)d_in[0];
  const float* enc_Wih0 = (const float*)d_in[1];
  const float* enc_Whh0 = (const float*)d_in[2];
  const float* enc_b0   = (const float*)d_in[3];
  const float* enc_Wih1 = (const float*)d_in[4];
  const float* enc_Whh1 = (const float*)d_in[5];
  const float* enc_b1   = (const float*)d_in[6];
  const float* dec_Wih0 = (const float*)d_in[7];
  const float* dec_Whh0 = (const float*)d_in[8];
  const float* dec_b0   = (const float*)d_in[9];
  const float* dec_Wih1 = (const float*)d_in[10];
  const float* dec_Whh1 = (const float*)d_in[11];
  const float* dec_b1   = (const float*)d_in[12];
  const float* fc_W     = (const float*)d_in[13];
  const float* fc_b     = (const float*)d_in[14];
  unsigned short* ws = (unsigned short*)d_ws;
  float* out = (float*)d_out;

  // 425,984 (hi,lo) pairs -> exactly 1664 blocks of 256
  prep_frag<<<1664, 256, 0, stream>>>(
      enc_Wih0, enc_Whh0, enc_b0, enc_Wih1, enc_Whh1,
      dec_Wih0, dec_Whh0, dec_b0, dec_Wih1, dec_Whh1, ws);

  lstm_mfma<<<NBLK, TPB, 0, stream>>>(
      x, ws, enc_b1, dec_b1, fc_W, fc_b, out);
}

// Round 9
// 6492.187 us; speedup vs baseline: 1.3187x; 1.3078x over previous
//
#include <hip/hip_runtime.h>
#include <cstdint>

typedef short short8  __attribute__((ext_vector_type(8)));
typedef unsigned short ushort4v __attribute__((ext_vector_type(4)));
typedef float floatx4 __attribute__((ext_vector_type(4)));

#define HID    128
#define NB     32
#define TPB    256
#define NBLK   2048          // 65536 / 32
#define TSTEPS 30
#define MU_OFF 5898240       // 65536*30*3

// ws layout (bf16 units): A-fragment-swizzled weight arrays, hi then lo per set
#define L0_SZ  81920         // 512*160  (K-ext: [Whh(128)|Wih0(3)|bias(1)|0(28)])
#define L1_SZ  131072        // 512*256  (K-ext: [Wih1(128)|Whh1(128)])
#define ENC0_HI 0
#define ENC0_LO 81920
#define ENC1_HI 163840
#define ENC1_LO 294912
#define DEC0_HI 425984
#define DEC0_LO 507904
#define DEC1_HI 589824
#define DEC1_LO 720896

#define S0 192               // h0 row stride (r4-proven): base ≡ 0 mod 32 dwords
#define S1 128               // h1 row stride

__device__ __forceinline__ float sigm(float v){ return 1.f/(1.f+__expf(-v)); }
__device__ __forceinline__ float tanh_fast(float v){ return 2.f/(1.f+__expf(-2.f*v)) - 1.f; }

__device__ __forceinline__ unsigned short f2bf(float f){
  unsigned u = __float_as_uint(f);
  u = (u + 0x7FFF + ((u>>16)&1)) >> 16;     // RNE; inputs finite
  return (unsigned short)u;
}
__device__ __forceinline__ float bf2f(unsigned short b){
  return __uint_as_float(((unsigned)b)<<16);
}

// ---------------- prep: swizzle weights into A-fragment order, bf16 hi/lo ----
// A-frag element (mt, kt, lane l, jj):  A[mt*16 + (l&15)][kt*32 + ((l>>4)&3)*8 + jj]
// stored at ((mt*KT + kt)*64 + l)*8 + jj   -> consumer does 1 coalesced b128/lane
// Layer0 K-ext columns: k<128 Whh | 128..130 Wih0 | 131 bias (B==1.0) | rest 0
extern "C" __global__ void __launch_bounds__(256)
prep_frag(const float* __restrict__ eWih0, const float* __restrict__ eWhh0,
          const float* __restrict__ eB0,
          const float* __restrict__ eWih1, const float* __restrict__ eWhh1,
          const float* __restrict__ dWih0, const float* __restrict__ dWhh0,
          const float* __restrict__ dB0,
          const float* __restrict__ dWih1, const float* __restrict__ dWhh1,
          unsigned short* __restrict__ ws)
{
  const int idx = blockIdx.x*256 + threadIdx.x;   // one thread -> one (hi,lo) pair
  int i2, hi_base, lo_base, KT;
  const float* Wa; const float* Wb; const float* Bv;
  if (idx < L0_SZ)                { i2=idx;                 hi_base=ENC0_HI; lo_base=ENC0_LO; Wa=eWhh0; Wb=eWih0; Bv=eB0; KT=5; }
  else if (idx < L0_SZ+L1_SZ)     { i2=idx-L0_SZ;           hi_base=ENC1_HI; lo_base=ENC1_LO; Wa=eWih1; Wb=eWhh1; Bv=0;   KT=8; }
  else if (idx < 2*L0_SZ+L1_SZ)   { i2=idx-(L0_SZ+L1_SZ);   hi_base=DEC0_HI; lo_base=DEC0_LO; Wa=dWhh0; Wb=dWih0; Bv=dB0; KT=5; }
  else                            { i2=idx-(2*L0_SZ+L1_SZ); hi_base=DEC1_HI; lo_base=DEC1_LO; Wa=dWih1; Wb=dWhh1; Bv=0;   KT=8; }
  const int jj = i2 & 7, l = (i2>>3)&63, tk = i2>>9;
  const int kt = (KT==5) ? (tk%5) : (tk&7);
  const int mt = (KT==5) ? (tk/5) : (tk>>3);
  const int row = mt*16 + (l&15);
  const int k   = kt*32 + ((l>>4)&3)*8 + jj;
  float w;
  if (KT==5){
    if      (k < 128) w = Wa[row*128+k];
    else if (k < 131) w = Wb[row*3 + (k-128)];
    else if (k ==131) w = Bv[row];
    else              w = 0.f;
  } else {
    w = (k<128) ? Wa[row*128+k] : Wb[row*128 + (k-128)];
  }
  const unsigned short hi = f2bf(w);
  ws[hi_base + i2] = hi;
  ws[lo_base + i2] = f2bf(w - bf2f(hi));
}

// ---------------- fused LSTM: NB=32/block, 4 waves, 3 blocks/CU -------------
extern "C" __global__ void __launch_bounds__(TPB, 3)
lstm_mfma(const float* __restrict__ x,
          const unsigned short* __restrict__ wf,
          const float* __restrict__ enc_b1, const float* __restrict__ dec_b1,
          const float* __restrict__ fc_W,  const float* __restrict__ fc_b,
          float* __restrict__ out)
{
  // h in B-frag layout: element (n,k) at n*S + ((k>>3)^(n&7))*8 + (k&7)
  // (holds for k<128 h, and for x/bias columns 128..131 via the same formula)
  __shared__ unsigned short h0h[NB*S0], h0l[NB*S0];   // 12288 B each
  __shared__ unsigned short h1h[NB*S1], h1l[NB*S1];   // 8192 B each
  __shared__ float bias1[512];                        // layer1 bias (enc, later dec)
  __shared__ float fcw[6*HID];
  __shared__ float fcb[8];

  const int tid  = threadIdx.x;
  const int w    = tid>>6, l = tid&63;
  const int quad = (l>>4)&3, n15 = l&15, q7 = n15&7;
  const int b0   = blockIdx.x*NB;

  for (int i=tid;i<512;i+=TPB) bias1[i]=enc_b1[i];
  for (int i=tid;i<6*HID;i+=TPB) fcw[i]=fc_W[i];
  if (tid<6) fcb[tid]=fc_b[tid];
  for (int i=tid;i<NB*S0;i+=TPB){ h0h[i]=0; h0l[i]=0; }
  for (int i=tid;i<NB*S1;i+=TPB){ h1h[i]=0; h1l[i]=0; }
  __syncthreads();
  // bias column (k=131) B==1.0, in the swizzled block 16 of each row
  if (tid < NB) h0h[tid*S0 + ((16^(tid&7))<<3) + 3] = 0x3F80;
  __syncthreads();

  auto write_x = [&](int t){
    if (tid < 96){
      const int n = tid & 31, c = tid >> 5;
      const float v = x[(size_t)(b0+n)*90 + t*3 + c];
      const int idx = n*S0 + ((16^(n&7))<<3) + c;     // k = 128+c -> block 16
      const unsigned short hi = f2bf(v);
      h0h[idx] = hi; h0l[idx] = f2bf(v - bf2f(hi));
    }
  };
  write_x(0);
  __syncthreads();

  // wave w owns m-tiles mt = g*8 + w*2 + s  (g=gate, s=0,1), i.e. j in [32w,32w+32)
  floatx4 acc[8][2];                 // [g*2+s][nt]
  float c0[2][2][4], c1[2][2][4];    // [s][nt][r]
#pragma unroll
  for (int s=0;s<2;s++)
#pragma unroll
    for (int nt=0;nt<2;nt++)
#pragma unroll
      for (int r=0;r<4;r++){ c0[s][nt][r]=0.f; c1[s][nt][r]=0.f; }

  auto zacc = [&]{
    const floatx4 z = {0.f,0.f,0.f,0.f};
#pragma unroll
    for (int p=0;p<8;p++){ acc[p][0]=z; acc[p][1]=z; }
  };

  // straight-line accumulate body: no conditionals, one code path
  auto mfma_block = [&](const unsigned short* __restrict__ Ahi,
                        const unsigned short* __restrict__ Alo, int KT, int kt,
                        const short8 (&bh)[2], const short8 (&bl)[2]){
#pragma unroll
    for (int p=0;p<8;p++){
      const int mt = (p>>1)*8 + w*2 + (p&1);
      const int ao = ((mt*KT + kt)*64 + l)*8;
      const short8 ah = *(const short8*)(Ahi + ao);
      const short8 al = *(const short8*)(Alo + ao);
      acc[p][0] = __builtin_amdgcn_mfma_f32_16x16x32_bf16(ah, bh[0], acc[p][0],0,0,0);
      acc[p][1] = __builtin_amdgcn_mfma_f32_16x16x32_bf16(ah, bh[1], acc[p][1],0,0,0);
      acc[p][0] = __builtin_amdgcn_mfma_f32_16x16x32_bf16(ah, bl[0], acc[p][0],0,0,0);
      acc[p][1] = __builtin_amdgcn_mfma_f32_16x16x32_bf16(ah, bl[1], acc[p][1],0,0,0);
      acc[p][0] = __builtin_amdgcn_mfma_f32_16x16x32_bf16(al, bh[0], acc[p][0],0,0,0);
      acc[p][1] = __builtin_amdgcn_mfma_f32_16x16x32_bf16(al, bh[1], acc[p][1],0,0,0);
    }
  };

  // layer0: K=160, 5 kt, all from h0 (kt=4 covers x cols 128-130, bias 131,
  // zeros beyond; quads 1-3 of kt=4 read don't-care blocks x zero A-weights)
  auto mv0 = [&](const unsigned short* __restrict__ Ahi,
                 const unsigned short* __restrict__ Alo){
    zacc();
#pragma unroll 1
    for (int kt=0; kt<5; ++kt){
      const int bo = (((kt*4+quad)^q7)<<3);
      short8 bh[2], bl[2];
#pragma unroll
      for (int nt=0;nt<2;nt++){
        const int ro = (nt*16+n15)*S0 + bo;
        bh[nt] = *(const short8*)(h0h + ro);
        bl[nt] = *(const short8*)(h0l + ro);
      }
      mfma_block(Ahi, Alo, 5, kt, bh, bl);
    }
  };

  // layer1: kt 0..3 from h0, kt 4..7 from h1
  auto mv1 = [&](const unsigned short* __restrict__ Ahi,
                 const unsigned short* __restrict__ Alo){
    zacc();
#pragma unroll 1
    for (int kt=0; kt<8; ++kt){
      const unsigned short* Bh = (kt<4) ? h0h : h1h;
      const unsigned short* Bl = (kt<4) ? h0l : h1l;
      const int SS  = (kt<4) ? S0 : S1;
      const int bo  = ((((kt&3)*4+quad)^q7)<<3);
      short8 bh[2], bl[2];
#pragma unroll
      for (int nt=0;nt<2;nt++){
        const int ro = (nt*16+n15)*SS + bo;
        bh[nt] = *(const short8*)(Bh + ro);
        bl[nt] = *(const short8*)(Bl + ro);
      }
      mfma_block(Ahi, Alo, 8, kt, bh, bl);
    }
  };

  // activations in-register; inner barrier, then packed b64 h-writes.
  // bs == nullptr: bias already folded into MFMA (layer0).
  auto cell_update = [&](float (&cst)[2][2][4], const float* bs,
                         unsigned short* Hh, unsigned short* Hl, int SS){
    float hv[2][2][4];
#pragma unroll
    for (int s=0;s<2;s++)
#pragma unroll
      for (int nt=0;nt<2;nt++)
#pragma unroll
        for (int r=0;r<4;r++){
          const int j = (w*2+s)*16 + quad*4 + r;
          float gi = acc[0+s][nt][r], gf = acc[2+s][nt][r];
          float gg = acc[4+s][nt][r], go = acc[6+s][nt][r];
          if (bs){ gi += bs[j]; gf += bs[128+j]; gg += bs[256+j]; go += bs[384+j]; }
          const float i_ = sigm(gi);
          const float f_ = sigm(gf);
          const float g_ = tanh_fast(gg);
          const float o_ = sigm(go);
          const float c  = f_*cst[s][nt][r] + i_*g_;
          cst[s][nt][r] = c;
          hv[s][nt][r]  = o_*tanh_fast(c);
        }
    __syncthreads();                 // all waves done READING old h
#pragma unroll
    for (int s=0;s<2;s++)
#pragma unroll
      for (int nt=0;nt<2;nt++){
        const int jb = (w*2+s)*2 + (quad>>1);        // j>>3
        const int n  = nt*16 + n15;
        const int base = n*SS + ((jb ^ (n&7))<<3) + ((quad&1)<<2);
        ushort4v ph, pl;
#pragma unroll
        for (int r=0;r<4;r++){
          const unsigned short hi = f2bf(hv[s][nt][r]);
          ph[r] = hi;
          pl[r] = f2bf(hv[s][nt][r] - bf2f(hi));
        }
        *(ushort4v*)(Hh + base) = ph;                // ds_write_b64
        *(ushort4v*)(Hl + base) = pl;
      }
  };

  // -------------------- encoder (3 barriers/timestep) --------------------
#pragma unroll 1
  for (int t=0; t<TSTEPS; ++t){
    mv0(wf+ENC0_HI, wf+ENC0_LO);
    cell_update(c0, nullptr, h0h, h0l, S0);
    if (t+1 < TSTEPS) write_x(t+1);      // x-block disjoint from h-block writes
    __syncthreads();
    mv1(wf+ENC1_HI, wf+ENC1_LO);
    cell_update(c1, bias1, h1h, h1l, S1);
    // no trailing barrier: next mv0 touches only h0/x; h1 visibility is
    // guaranteed by the two barriers inside the next timestep before mv1.
  }
  // h0 x-block still holds x[:,29,:] == decoder's initial input

  // refill bias1 with decoder layer-1 bias: all enc bias1 reads precede the
  // internal barrier of the last cell_update, which every wave has passed.
  for (int i=tid;i<512;i+=TPB) bias1[i]=dec_b1[i];
  __syncthreads();

  // -------------------- decoder --------------------
#pragma unroll 1
  for (int t=0; t<TSTEPS; ++t){
    mv0(wf+DEC0_HI, wf+DEC0_LO);
    cell_update(c0, nullptr, h0h, h0l, S0);
    __syncthreads();
    mv1(wf+DEC1_HI, wf+DEC1_LO);
    cell_update(c1, bias1, h1h, h1l, S1);
    __syncthreads();                     // h1_t visible for FC

    // FC head: stats[6][32] = fcW @ h1 + fcb; mu fed back into h0 x-block
    if (tid < 192){
      const int n = tid & 31, oi = tid >> 5;
      float s = fcb[oi];
#pragma unroll 4
      for (int blk=0; blk<16; ++blk){
        const int ro = n*S1 + ((blk^(n&7))<<3);
        const short8 hh = *(const short8*)(h1h + ro);
        const short8 hl = *(const short8*)(h1l + ro);
#pragma unroll
        for (int jj=0;jj<8;++jj)
          s += fcw[oi*HID + blk*8 + jj] *
               (bf2f((unsigned short)hh[jj]) + bf2f((unsigned short)hl[jj]));
      }
      const size_t off = (size_t)(b0+n)*90 + (size_t)t*3;
      if (oi < 3){
        out[off + oi] = s;
        const int idx = n*S0 + ((16^(n&7))<<3) + oi;  // k = 128+oi
        const unsigned short hi = f2bf(s);
        h0h[idx] = hi; h0l[idx] = f2bf(s - bf2f(hi));
      } else {
        out[MU_OFF + off + (oi-3)] = s;
      }
    }
    __syncthreads();
  }
}

extern "C" void kernel_launch(void* const* d_in, const int* in_sizes, int n_in,
                              void* d_out, int out_size, void* d_ws, size_t ws_size,
                              hipStream_t stream) {
  const float* x        = (const float*)d_in[0];
  const float* enc_Wih0 = (const float*)d_in[1];
  const float* enc_Whh0 = (const float*)d_in[2];
  const float* enc_b0   = (const float*)d_in[3];
  const float* enc_Wih1 = (const float*)d_in[4];
  const float* enc_Whh1 = (const float*)d_in[5];
  const float* enc_b1   = (const float*)d_in[6];
  const float* dec_Wih0 = (const float*)d_in[7];
  const float* dec_Whh0 = (const float*)d_in[8];
  const float* dec_b0   = (const float*)d_in[9];
  const float* dec_Wih1 = (const float*)d_in[10];
  const float* dec_Whh1 = (const float*)d_in[11];
  const float* dec_b1   = (const float*)d_in[12];
  const float* fc_W     = (const float*)d_in[13];
  const float* fc_b     = (const float*)d_in[14];
  unsigned short* ws = (unsigned short*)d_ws;
  float* out = (float*)d_out;

  // 425,984 (hi,lo) pairs -> exactly 1664 blocks of 256
  prep_frag<<<1664, 256, 0, stream>>>(
      enc_Wih0, enc_Whh0, enc_b0, enc_Wih1, enc_Whh1,
      dec_Wih0, dec_Whh0, dec_b0, dec_Wih1, dec_Whh1, ws);

  lstm_mfma<<<NBLK, TPB, 0, stream>>>(
      x, ws, enc_b1, dec_b1, fc_W, fc_b, out);
}